// Round 1
// baseline (2871.647 us; speedup 1.0000x reference)
//
#include <hip/hip_runtime.h>

#define N_NODES 100000
#define N_EDGES 1600000
#define D 64

// ---------------- degree / norm precompute ----------------

__global__ void deg_init(float* __restrict__ deg) {
    int i = blockIdx.x * 256 + threadIdx.x;
    if (i < N_NODES) deg[i] = 1.0f;  // self-loop weight contributes 1 to every node
}

__global__ void deg_scatter(const int* __restrict__ col, const float* __restrict__ w,
                            float* __restrict__ deg) {
    int e = blockIdx.x * 256 + threadIdx.x;
    if (e < N_EDGES) atomicAdd(&deg[col[e]], w[e]);
}

__global__ void dinv_kernel(float* __restrict__ deg) {
    int i = blockIdx.x * 256 + threadIdx.x;
    if (i < N_NODES) {
        float d = deg[i];
        deg[i] = (d > 0.0f) ? rsqrtf(fmaxf(d, 1e-12f)) : 0.0f;
    }
}

__global__ void norm_kernel(const int* __restrict__ row, const int* __restrict__ col,
                            const float* __restrict__ w, const float* __restrict__ dinv,
                            float* __restrict__ norm) {
    int e = blockIdx.x * 256 + threadIdx.x;
    if (e < N_EDGES) norm[e] = dinv[row[e]] * w[e] * dinv[col[e]];
}

// ---------------- dense transform: out = (relu? max(in,0):in) @ W ----------------
// W is [D][D] row-major (W[k][d]). Block: 256 threads = 4 rows x 64 cols.

template <bool RELU>
__global__ void gemm_kernel(const float* __restrict__ in, const float* __restrict__ W,
                            float* __restrict__ out) {
    __shared__ float Ws[D * D];
    __shared__ float xs[4][D];
    int t = threadIdx.x;
    for (int i = t; i < D * D; i += 256) Ws[i] = W[i];
    int ty = t >> 6;       // row within block (0..3)
    int d  = t & 63;       // output column
    int n  = blockIdx.x * 4 + ty;
    if (n < N_NODES) {
        float v = in[n * D + d];
        xs[ty][d] = RELU ? fmaxf(v, 0.0f) : v;
    }
    __syncthreads();
    if (n >= N_NODES) return;
    float acc = 0.0f;
#pragma unroll
    for (int k = 0; k < D; ++k) acc += xs[ty][k] * Ws[k * D + d];
    out[n * D + d] = acc;
}

// ---------------- aggregation ----------------
// out[i][d] = b[d] + dinv[i]^2 * h[i][d]   (bias + self-loop edge), full overwrite
__global__ void agg_init(const float4* __restrict__ h4, const float* __restrict__ b,
                         const float* __restrict__ dinv, float4* __restrict__ out4) {
    int gid = blockIdx.x * 256 + threadIdx.x;   // one float4 per thread
    if (gid >= N_NODES * (D / 4)) return;
    int node = gid >> 4;
    int ch   = gid & 15;
    float s = dinv[node];
    s = s * s;
    float4 hv = h4[gid];
    float4 bv = ((const float4*)b)[ch];
    float4 o;
    o.x = bv.x + s * hv.x;
    o.y = bv.y + s * hv.y;
    o.z = bv.z + s * hv.z;
    o.w = bv.w + s * hv.w;
    out4[gid] = o;
}

// out[col[e]][:] += norm[e] * h[row[e]][:]  — 16 threads per edge, float4 each
__global__ void edge_scatter(const int* __restrict__ row, const int* __restrict__ col,
                             const float* __restrict__ norm, const float4* __restrict__ h4,
                             float* __restrict__ out) {
    int gid = blockIdx.x * 256 + threadIdx.x;
    if (gid >= N_EDGES * 16) return;
    int e  = gid >> 4;
    int ch = gid & 15;
    int r = row[e];
    int c = col[e];
    float nv = norm[e];
    float4 hv = h4[r * 16 + ch];
    float* op = out + c * D + ch * 4;
    atomicAdd(op + 0, nv * hv.x);
    atomicAdd(op + 1, nv * hv.y);
    atomicAdd(op + 2, nv * hv.z);
    atomicAdd(op + 3, nv * hv.w);
}

__global__ void relu_kernel(float4* __restrict__ v4, int n4) {
    int gid = blockIdx.x * 256 + threadIdx.x;
    if (gid >= n4) return;
    float4 v = v4[gid];
    v.x = fmaxf(v.x, 0.0f);
    v.y = fmaxf(v.y, 0.0f);
    v.z = fmaxf(v.z, 0.0f);
    v.w = fmaxf(v.w, 0.0f);
    v4[gid] = v;
}

extern "C" void kernel_launch(void* const* d_in, const int* in_sizes, int n_in,
                              void* d_out, int out_size, void* d_ws, size_t ws_size,
                              hipStream_t stream) {
    const float* x       = (const float*)d_in[0];
    const int*   adj     = (const int*)d_in[1];    // [2][E]
    const float* adj_wts = (const float*)d_in[2];
    const float* W1      = (const float*)d_in[3];
    const float* b1      = (const float*)d_in[4];
    const float* W2      = (const float*)d_in[5];
    const float* b2      = (const float*)d_in[6];
    float* out = (float*)d_out;

    const int* row = adj;
    const int* col = adj + N_EDGES;

    float* dinv = (float*)d_ws;                 // N floats
    float* norm = dinv + N_NODES;               // E floats
    float* h    = norm + N_EDGES;               // N*D floats
    float* agg1 = h + (size_t)N_NODES * D;      // N*D floats

    const int nblk_n  = (N_NODES + 255) / 256;
    const int nblk_e  = (N_EDGES + 255) / 256;
    const int nblk_nd = (N_NODES * 16 + 255) / 256;   // N*D/4 float4s
    const int nblk_ed = (N_EDGES * 16) / 256;         // exactly 100000
    const int nblk_g  = (N_NODES + 3) / 4;

    // norm precompute (shared by both layers)
    deg_init<<<nblk_n, 256, 0, stream>>>(dinv);
    deg_scatter<<<nblk_e, 256, 0, stream>>>(col, adj_wts, dinv);
    dinv_kernel<<<nblk_n, 256, 0, stream>>>(dinv);
    norm_kernel<<<nblk_e, 256, 0, stream>>>(row, col, adj_wts, dinv, norm);

    // layer 1: h = x @ W1 ; agg1 = segsum(norm * h[row]) + b1
    gemm_kernel<false><<<nblk_g, 256, 0, stream>>>(x, W1, h);
    agg_init<<<nblk_nd, 256, 0, stream>>>((const float4*)h, b1, dinv, (float4*)agg1);
    edge_scatter<<<nblk_ed, 256, 0, stream>>>(row, col, norm, (const float4*)h, agg1);

    // layer 2: h = relu(agg1) @ W2 ; out = segsum(norm * h[row]) + b2 ; relu
    gemm_kernel<true><<<nblk_g, 256, 0, stream>>>(agg1, W2, h);
    agg_init<<<nblk_nd, 256, 0, stream>>>((const float4*)h, b2, dinv, (float4*)out);
    edge_scatter<<<nblk_ed, 256, 0, stream>>>(row, col, norm, (const float4*)h, out);
    relu_kernel<<<nblk_nd, 256, 0, stream>>>((float4*)out, N_NODES * 16);
}

// Round 2
// 501.501 us; speedup vs baseline: 5.7261x; 5.7261x over previous
//
#include <hip/hip_runtime.h>

#define N_NODES 100000
#define N_EDGES 1600000
#define D 64

// ---------------- init: dinv=1 (self-loop weight), cnt=0, cursor=0 ----------------
__global__ void init_kernel(float* __restrict__ deg, int* __restrict__ cnt,
                            int* __restrict__ cursor) {
    int i = blockIdx.x * 256 + threadIdx.x;
    if (i < N_NODES) { deg[i] = 1.0f; cnt[i] = 0; cursor[i] = 0; }
}

// ---------------- degree (weighted) + in-degree count ----------------
__global__ void deg_cnt_scatter(const int* __restrict__ col, const float* __restrict__ w,
                                float* __restrict__ deg, int* __restrict__ cnt) {
    int e = blockIdx.x * 256 + threadIdx.x;
    if (e < N_EDGES) {
        int c = col[e];
        atomicAdd(&deg[c], w[e]);
        atomicAdd(&cnt[c], 1);
    }
}

__global__ void dinv_kernel(float* __restrict__ deg) {
    int i = blockIdx.x * 256 + threadIdx.x;
    if (i < N_NODES) {
        float d = deg[i];
        deg[i] = (d > 0.0f) ? rsqrtf(fmaxf(d, 1e-12f)) : 0.0f;
    }
}

// ---------------- exclusive scan of cnt -> base (3 kernels) ----------------
__global__ void scan1(const int* __restrict__ cnt, int* __restrict__ base,
                      int* __restrict__ bsum) {
    __shared__ int s[256];
    int tid = threadIdx.x;
    int i = blockIdx.x * 256 + tid;
    int v = (i < N_NODES) ? cnt[i] : 0;
    s[tid] = v;
    __syncthreads();
    for (int o = 1; o < 256; o <<= 1) {
        int t = (tid >= o) ? s[tid - o] : 0;
        __syncthreads();
        s[tid] += t;
        __syncthreads();
    }
    if (i < N_NODES) base[i] = s[tid] - v;   // exclusive
    if (tid == 255) bsum[blockIdx.x] = s[255];
}

__global__ void scan2(int* __restrict__ bsum, int* __restrict__ base, int nblocks) {
    __shared__ int s[512];
    int tid = threadIdx.x;
    int v = (tid < nblocks) ? bsum[tid] : 0;
    s[tid] = v;
    __syncthreads();
    for (int o = 1; o < 512; o <<= 1) {
        int t = (tid >= o) ? s[tid - o] : 0;
        __syncthreads();
        s[tid] += t;
        __syncthreads();
    }
    if (tid < nblocks) bsum[tid] = s[tid] - v;  // exclusive block offsets
    if (tid == 0) base[N_NODES] = N_EDGES;
}

__global__ void scan3(int* __restrict__ base, const int* __restrict__ bsum) {
    int i = blockIdx.x * 256 + threadIdx.x;
    if (i < N_NODES) base[i] += bsum[blockIdx.x];
}

// ---------------- CSR scatter: epack[pos] = {src, norm} grouped by dest ----------------
__global__ void csr_scatter(const int* __restrict__ row, const int* __restrict__ col,
                            const float* __restrict__ w, const float* __restrict__ dinv,
                            const int* __restrict__ base, int* __restrict__ cursor,
                            int2* __restrict__ epack) {
    int e = blockIdx.x * 256 + threadIdx.x;
    if (e >= N_EDGES) return;
    int r = row[e];
    int c = col[e];
    float nv = dinv[r] * w[e] * dinv[c];
    int pos = base[c] + atomicAdd(&cursor[c], 1);
    int2 p;
    p.x = r;
    p.y = __float_as_int(nv);
    epack[pos] = p;
}

// ---------------- dense transform: out = (relu? max(in,0):in) @ W ----------------
template <bool RELU>
__global__ void gemm_kernel(const float* __restrict__ in, const float* __restrict__ W,
                            float* __restrict__ out) {
    __shared__ float Ws[D * D];
    __shared__ float xs[4][D];
    int t = threadIdx.x;
    for (int i = t; i < D * D; i += 256) Ws[i] = W[i];
    int ty = t >> 6;
    int d  = t & 63;
    int n  = blockIdx.x * 4 + ty;
    if (n < N_NODES) {
        float v = in[n * D + d];
        xs[ty][d] = RELU ? fmaxf(v, 0.0f) : v;
    }
    __syncthreads();
    if (n >= N_NODES) return;
    float acc = 0.0f;
#pragma unroll
    for (int k = 0; k < D; ++k) acc += xs[ty][k] * Ws[k * D + d];
    out[n * D + d] = acc;
}

// ---------------- gather aggregation: one wave per node, lane = channel ----------------
// out[i][d] = b[d] + dinv[i]^2*h[i][d] + sum_k norm_k * h[src_k][d]
template <bool RELU_OUT>
__global__ void agg_gather(const float* __restrict__ h, const float* __restrict__ b,
                           const float* __restrict__ dinv, const int2* __restrict__ epack,
                           const int* __restrict__ base, float* __restrict__ out) {
    int t = threadIdx.x;
    int node = blockIdx.x * 4 + (t >> 6);
    int d = t & 63;
    if (node >= N_NODES) return;
    float s = dinv[node];
    float acc = b[d] + s * s * h[node * D + d];
    int k  = base[node];
    int en = base[node + 1];
#pragma unroll 4
    for (; k < en; ++k) {
        int2 p = epack[k];                 // broadcast 8B load (same addr all lanes)
        acc = fmaf(__int_as_float(p.y), h[p.x * D + d], acc);
    }
    if (RELU_OUT) acc = fmaxf(acc, 0.0f);
    out[node * D + d] = acc;
}

extern "C" void kernel_launch(void* const* d_in, const int* in_sizes, int n_in,
                              void* d_out, int out_size, void* d_ws, size_t ws_size,
                              hipStream_t stream) {
    const float* x       = (const float*)d_in[0];
    const int*   adj     = (const int*)d_in[1];    // [2][E]
    const float* adj_wts = (const float*)d_in[2];
    const float* W1      = (const float*)d_in[3];
    const float* b1      = (const float*)d_in[4];
    const float* W2      = (const float*)d_in[5];
    const float* b2      = (const float*)d_in[6];
    float* out = (float*)d_out;

    const int* row = adj;
    const int* col = adj + N_EDGES;

    // workspace layout (all 16B-aligned: N_NODES*4 = 400000 B, mult of 16)
    float* dinv   = (float*)d_ws;                       // N floats
    int*   cnt    = (int*)(dinv + N_NODES);             // N ints
    int*   cursor = cnt + N_NODES;                      // N ints
    int*   base   = cursor + N_NODES;                   // N+1 ints (pad 4)
    int*   bsum   = base + N_NODES + 4;                 // 512 ints
    int2*  epack  = (int2*)(bsum + 512);                // E int2 (12.8 MB)
    float* h      = (float*)(epack + N_EDGES);          // N*D floats (25.6 MB)
    float* agg1   = h + (size_t)N_NODES * D;            // N*D floats (25.6 MB)

    const int nblk_n  = (N_NODES + 255) / 256;          // 391
    const int nblk_e  = (N_EDGES + 255) / 256;
    const int nblk_g  = (N_NODES + 3) / 4;              // 25000

    // ---- CSR + norm build (once, shared by both layers) ----
    init_kernel<<<nblk_n, 256, 0, stream>>>(dinv, cnt, cursor);
    deg_cnt_scatter<<<nblk_e, 256, 0, stream>>>(col, adj_wts, dinv, cnt);
    dinv_kernel<<<nblk_n, 256, 0, stream>>>(dinv);
    scan1<<<nblk_n, 256, 0, stream>>>(cnt, base, bsum);
    scan2<<<1, 512, 0, stream>>>(bsum, base, nblk_n);
    scan3<<<nblk_n, 256, 0, stream>>>(base, bsum);
    csr_scatter<<<nblk_e, 256, 0, stream>>>(row, col, adj_wts, dinv, base, cursor, epack);

    // ---- layer 1 ----
    gemm_kernel<false><<<nblk_g, 256, 0, stream>>>(x, W1, h);
    agg_gather<false><<<nblk_g, 256, 0, stream>>>(h, b1, dinv, epack, base, agg1);

    // ---- layer 2 ----
    gemm_kernel<true><<<nblk_g, 256, 0, stream>>>(agg1, W2, h);
    agg_gather<true><<<nblk_g, 256, 0, stream>>>(h, b2, dinv, epack, base, out);
}

// Round 3
// 340.561 us; speedup vs baseline: 8.4321x; 1.4726x over previous
//
#include <hip/hip_runtime.h>

#define N_NODES 100000
#define N_EDGES 1600000
#define D 64

// ---------------- CSR build ----------------

__global__ void zero_cnt(int* __restrict__ cnt) {
    int i = blockIdx.x * 256 + threadIdx.x;
    if (i < N_NODES) cnt[i] = 0;
}

// rank[e] = arrival index of edge e at its destination (the ONLY atomic pass)
__global__ void count_rank(const int* __restrict__ col, int* __restrict__ cnt,
                           int* __restrict__ rank) {
    int e = blockIdx.x * 256 + threadIdx.x;
    if (e < N_EDGES) rank[e] = atomicAdd(&cnt[col[e]], 1);
}

// exclusive scan of cnt -> base (3 kernels)
__global__ void scan1(const int* __restrict__ cnt, int* __restrict__ base,
                      int* __restrict__ bsum) {
    __shared__ int s[256];
    int tid = threadIdx.x;
    int i = blockIdx.x * 256 + tid;
    int v = (i < N_NODES) ? cnt[i] : 0;
    s[tid] = v;
    __syncthreads();
    for (int o = 1; o < 256; o <<= 1) {
        int t = (tid >= o) ? s[tid - o] : 0;
        __syncthreads();
        s[tid] += t;
        __syncthreads();
    }
    if (i < N_NODES) base[i] = s[tid] - v;   // exclusive
    if (tid == 255) bsum[blockIdx.x] = s[255];
}

__global__ void scan2(int* __restrict__ bsum, int* __restrict__ base, int nblocks) {
    __shared__ int s[512];
    int tid = threadIdx.x;
    int v = (tid < nblocks) ? bsum[tid] : 0;
    s[tid] = v;
    __syncthreads();
    for (int o = 1; o < 512; o <<= 1) {
        int t = (tid >= o) ? s[tid - o] : 0;
        __syncthreads();
        s[tid] += t;
        __syncthreads();
    }
    if (tid < nblocks) bsum[tid] = s[tid] - v;  // exclusive block offsets
    if (tid == 0) base[N_NODES] = N_EDGES;
}

__global__ void scan3(int* __restrict__ base, const int* __restrict__ bsum) {
    int i = blockIdx.x * 256 + threadIdx.x;
    if (i < N_NODES) base[i] += bsum[blockIdx.x];
}

// epack[base[col]+rank] = {src, raw_weight}  — no atomics
__global__ void scatter_sw(const int* __restrict__ row, const int* __restrict__ col,
                           const float* __restrict__ w, const int* __restrict__ rank,
                           const int* __restrict__ base, int2* __restrict__ epack) {
    int e = blockIdx.x * 256 + threadIdx.x;
    if (e >= N_EDGES) return;
    int c = col[e];
    int pos = base[c] + rank[e];
    int2 p;
    p.x = row[e];
    p.y = __float_as_int(w[e]);
    epack[pos] = p;
}

// dinv[i] = rsqrt(1 + sum of incoming weights) — gather over CSR, no atomics
__global__ void deg_dinv(const int2* __restrict__ epack, const int* __restrict__ base,
                         float* __restrict__ dinv) {
    int i = blockIdx.x * 256 + threadIdx.x;
    if (i >= N_NODES) return;
    float s = 1.0f;  // self-loop weight
    int en = base[i + 1];
    for (int k = base[i]; k < en; ++k) s += __int_as_float(epack[k].y);
    dinv[i] = rsqrtf(s);
}

// ---------------- fused layer: out = relu( agg(x) @ W + b ) ----------------
// agg(x)[i] = dinv[i]^2 * x[i] + sum_e dinv[src]*w*dinv[i] * x[src]
//           = dinv[i] * ( dinv[i]*x[i] + sum_e dinv[src]*w * x[src] )
// One wave per node (lane = channel). 4 nodes per 256-thread block.
__global__ __launch_bounds__(256, 4)
void gcn_layer(const float* __restrict__ xin, const float* __restrict__ W,
               const float* __restrict__ b, const float* __restrict__ dinv,
               const int2* __restrict__ epack, const int* __restrict__ base,
               float* __restrict__ out) {
    __shared__ float Ws[D * D];
    __shared__ float xs[4][D];
    int t = threadIdx.x;
    for (int i = t; i < D * D; i += 256) Ws[i] = W[i];
    int ty = t >> 6;
    int d  = t & 63;
    int node = blockIdx.x * 4 + ty;        // N_NODES % 4 == 0: always valid
    float s   = dinv[node];
    float bd  = b[d];
    float acc = s * xin[node * D + d];     // self term (x *dinv; another *dinv below)
#pragma unroll 4
    for (int k = base[node], en = base[node + 1]; k < en; ++k) {
        int2 p = epack[k];                              // 8B broadcast
        float nv = dinv[p.x] * __int_as_float(p.y);     // 4B broadcast gather
        acc = fmaf(nv, xin[p.x * D + d], acc);          // 256B coalesced gather
    }
    xs[ty][d] = s * acc;                   // aggregated feature row in LDS
    __syncthreads();                       // also covers the Ws staging
    float y = bd;
#pragma unroll
    for (int k = 0; k < D; ++k) y = fmaf(xs[ty][k], Ws[k * D + d], y);
    out[node * D + d] = fmaxf(y, 0.0f);
}

extern "C" void kernel_launch(void* const* d_in, const int* in_sizes, int n_in,
                              void* d_out, int out_size, void* d_ws, size_t ws_size,
                              hipStream_t stream) {
    const float* x       = (const float*)d_in[0];
    const int*   adj     = (const int*)d_in[1];    // [2][E]
    const float* adj_wts = (const float*)d_in[2];
    const float* W1      = (const float*)d_in[3];
    const float* b1      = (const float*)d_in[4];
    const float* W2      = (const float*)d_in[5];
    const float* b2      = (const float*)d_in[6];
    float* out = (float*)d_out;

    const int* row = adj;
    const int* col = adj + N_EDGES;

    // workspace layout (N_NODES*4 = 400000 B keeps 16B alignment)
    int*   cnt   = (int*)d_ws;                      // N
    int*   rank  = cnt + N_NODES;                   // E
    int*   base  = rank + N_EDGES;                  // N+1 (+pad)
    int*   bsum  = base + N_NODES + 4;              // 512
    float* dinv  = (float*)(bsum + 512);            // N
    int2*  epack = (int2*)(dinv + N_NODES);         // E int2 (12.8 MB)
    float* h     = (float*)(epack + N_EDGES);       // N*D (25.6 MB)

    const int nblk_n = (N_NODES + 255) / 256;       // 391
    const int nblk_e = (N_EDGES + 255) / 256;       // 6250
    const int nblk_g = N_NODES / 4;                 // 25000

    // ---- CSR build (one atomic per edge) ----
    zero_cnt<<<nblk_n, 256, 0, stream>>>(cnt);
    count_rank<<<nblk_e, 256, 0, stream>>>(col, cnt, rank);
    scan1<<<nblk_n, 256, 0, stream>>>(cnt, base, bsum);
    scan2<<<1, 512, 0, stream>>>(bsum, base, nblk_n);
    scan3<<<nblk_n, 256, 0, stream>>>(base, bsum);
    scatter_sw<<<nblk_e, 256, 0, stream>>>(row, col, adj_wts, rank, base, epack);
    deg_dinv<<<nblk_n, 256, 0, stream>>>(epack, base, dinv);

    // ---- fused layers ----
    gcn_layer<<<nblk_g, 256, 0, stream>>>(x, W1, b1, dinv, epack, base, h);
    gcn_layer<<<nblk_g, 256, 0, stream>>>(h, W2, b2, dinv, epack, base, out);
}